// Round 5
// baseline (85.377 us; speedup 1.0000x reference)
//
#include <hip/hip_runtime.h>
#include <hip/hip_bf16.h>
#include <cstdint>
#include <cstddef>

#define NNODES 4096
#define NHEADS 4
#define NBR_STRIDE 128

typedef __attribute__((ext_vector_type(8))) short bf16x8v;
typedef __attribute__((ext_vector_type(4))) float f32x4;

__device__ inline unsigned short bf16_rn(float f) {
    unsigned int u = __float_as_uint(f);
    u += 0x7FFFu + ((u >> 16) & 1u);
    return (unsigned short)(u >> 16);
}
__device__ inline float bf16_f32(unsigned short s) {
    return __uint_as_float(((unsigned int)s) << 16);
}

// ---------------------------------------------------------------------------
// build_nbr body: one wave handles one adjacency row (4 rows per block).
// ---------------------------------------------------------------------------
__device__ inline void build_nbr_body(
    const float* __restrict__ adj, int* __restrict__ nbr, int* __restrict__ deg,
    int rowblk) {
    int wave = threadIdx.x >> 6;
    int lane = threadIdx.x & 63;
    int row = rowblk * 4 + wave;
    const float4* arow = reinterpret_cast<const float4*>(adj + (size_t)row * NNODES);
    unsigned long long lt = (1ull << lane) - 1ull;
    int base = 0;
    #pragma unroll 4
    for (int it = 0; it < NNODES / 256; ++it) {
        float4 v = arow[it * 64 + lane];
        bool b0 = v.x > 0.f, b1 = v.y > 0.f, b2 = v.z > 0.f, b3 = v.w > 0.f;
        unsigned long long m0 = __ballot(b0);
        unsigned long long m1 = __ballot(b1);
        unsigned long long m2 = __ballot(b2);
        unsigned long long m3 = __ballot(b3);
        int pre = __popcll(m0 & lt) + __popcll(m1 & lt) +
                  __popcll(m2 & lt) + __popcll(m3 & lt);
        int pos = base + pre;
        int colb = it * 256 + lane * 4;
        if (b0) { if (pos < NBR_STRIDE) nbr[row * NBR_STRIDE + pos] = colb;     pos++; }
        if (b1) { if (pos < NBR_STRIDE) nbr[row * NBR_STRIDE + pos] = colb + 1; pos++; }
        if (b2) { if (pos < NBR_STRIDE) nbr[row * NBR_STRIDE + pos] = colb + 2; pos++; }
        if (b3) { if (pos < NBR_STRIDE) nbr[row * NBR_STRIDE + pos] = colb + 3; pos++; }
        base += __popcll(m0) + __popcll(m1) + __popcll(m2) + __popcll(m3);
    }
    if (lane == 0) deg[row] = base < NBR_STRIDE ? base : NBR_STRIDE;
}

// ---------------------------------------------------------------------------
// gemm body: C[M,N] = A[M,K](f32) * Wp^T via in-LDS hi/lo split, bf16 MFMA
// (hi*hi + hi*lo + lo*hi). W layout [H][K][FO], f32 — split done in-kernel.
// BM=32, BN=64, BK=64; 4 waves, wave = 16 rows x 32 cols (2 frags).
// Epilogue: writes C AND per-row attention dots asrc/adst (fused adot).
// ---------------------------------------------------------------------------
template <int K, int N, int FO>
__device__ inline void gemm_body(
    const float* __restrict__ A, const float* __restrict__ W,
    const float* __restrict__ a, float* __restrict__ C,
    float* __restrict__ asrc, float* __restrict__ adst,
    int bx, int by) {
    constexpr int BM = 32, BN = 64, BK = 64, LP = BK + 8;
    __shared__ unsigned short Alh[BM][LP], All[BM][LP];
    __shared__ unsigned short Blh[BN][LP], Bll[BN][LP];
    __shared__ float reds[2][BM], redd[2][BM];
    int tid = threadIdx.x;
    int wave = tid >> 6, lane = tid & 63;
    int rowBase = bx * BM;
    int colBase = by * BN;
    int wr = wave >> 1, wc = wave & 1;
    int lr = lane & 15, lk = lane >> 4;
    f32x4 acc0 = {0.f, 0.f, 0.f, 0.f};
    f32x4 acc1 = {0.f, 0.f, 0.f, 0.f};
    int ar = tid >> 3;            // 0..31 (A row)
    int ac = (tid & 7) * 8;       // A col chunk (8 floats)
    for (int k0 = 0; k0 < K; k0 += BK) {
        float4 a0 = *reinterpret_cast<const float4*>(&A[(size_t)(rowBase + ar) * K + k0 + ac]);
        float4 a1 = *reinterpret_cast<const float4*>(&A[(size_t)(rowBase + ar) * K + k0 + ac + 4]);
        // B tile loads: 64 k-rows x 64 cols f32 from W, head-aligned float4s
        float4 bw[4];
        int bkr[4], bc4[4], bo[4], bh[4];
        #pragma unroll
        for (int i = 0; i < 4; ++i) {
            int idx = tid + i * 256;
            bkr[i] = idx >> 4;
            bc4[i] = (idx & 15) * 4;
            int n0 = colBase + bc4[i];
            bh[i] = n0 / FO;
            bo[i] = n0 % FO;
            bw[i] = *reinterpret_cast<const float4*>(
                &W[((size_t)bh[i] * K + k0 + bkr[i]) * FO + bo[i]]);
        }
        __syncthreads();   // previous iteration's readers done
        ushort4 h4, l4;
        h4.x = bf16_rn(a0.x); l4.x = bf16_rn(a0.x - bf16_f32(h4.x));
        h4.y = bf16_rn(a0.y); l4.y = bf16_rn(a0.y - bf16_f32(h4.y));
        h4.z = bf16_rn(a0.z); l4.z = bf16_rn(a0.z - bf16_f32(h4.z));
        h4.w = bf16_rn(a0.w); l4.w = bf16_rn(a0.w - bf16_f32(h4.w));
        *reinterpret_cast<ushort4*>(&Alh[ar][ac]) = h4;
        *reinterpret_cast<ushort4*>(&All[ar][ac]) = l4;
        h4.x = bf16_rn(a1.x); l4.x = bf16_rn(a1.x - bf16_f32(h4.x));
        h4.y = bf16_rn(a1.y); l4.y = bf16_rn(a1.y - bf16_f32(h4.y));
        h4.z = bf16_rn(a1.z); l4.z = bf16_rn(a1.z - bf16_f32(h4.z));
        h4.w = bf16_rn(a1.w); l4.w = bf16_rn(a1.w - bf16_f32(h4.w));
        *reinterpret_cast<ushort4*>(&Alh[ar][ac + 4]) = h4;
        *reinterpret_cast<ushort4*>(&All[ar][ac + 4]) = l4;
        #pragma unroll
        for (int i = 0; i < 4; ++i) {
            float4 v = bw[i];
            unsigned short hh, ll;
            hh = bf16_rn(v.x); ll = bf16_rn(v.x - bf16_f32(hh));
            Blh[bc4[i] + 0][bkr[i]] = hh; Bll[bc4[i] + 0][bkr[i]] = ll;
            hh = bf16_rn(v.y); ll = bf16_rn(v.y - bf16_f32(hh));
            Blh[bc4[i] + 1][bkr[i]] = hh; Bll[bc4[i] + 1][bkr[i]] = ll;
            hh = bf16_rn(v.z); ll = bf16_rn(v.z - bf16_f32(hh));
            Blh[bc4[i] + 2][bkr[i]] = hh; Bll[bc4[i] + 2][bkr[i]] = ll;
            hh = bf16_rn(v.w); ll = bf16_rn(v.w - bf16_f32(hh));
            Blh[bc4[i] + 3][bkr[i]] = hh; Bll[bc4[i] + 3][bkr[i]] = ll;
        }
        __syncthreads();
        #pragma unroll
        for (int ks = 0; ks < 2; ++ks) {
            int kb = ks * 32 + lk * 8;
            bf16x8v ah = *reinterpret_cast<const bf16x8v*>(&Alh[wr * 16 + lr][kb]);
            bf16x8v al = *reinterpret_cast<const bf16x8v*>(&All[wr * 16 + lr][kb]);
            bf16x8v b0h = *reinterpret_cast<const bf16x8v*>(&Blh[wc * 32 + lr][kb]);
            bf16x8v b0l = *reinterpret_cast<const bf16x8v*>(&Bll[wc * 32 + lr][kb]);
            bf16x8v b1h = *reinterpret_cast<const bf16x8v*>(&Blh[wc * 32 + 16 + lr][kb]);
            bf16x8v b1l = *reinterpret_cast<const bf16x8v*>(&Bll[wc * 32 + 16 + lr][kb]);
            acc0 = __builtin_amdgcn_mfma_f32_16x16x32_bf16(ah, b0h, acc0, 0, 0, 0);
            acc0 = __builtin_amdgcn_mfma_f32_16x16x32_bf16(ah, b0l, acc0, 0, 0, 0);
            acc0 = __builtin_amdgcn_mfma_f32_16x16x32_bf16(al, b0h, acc0, 0, 0, 0);
            acc1 = __builtin_amdgcn_mfma_f32_16x16x32_bf16(ah, b1h, acc1, 0, 0, 0);
            acc1 = __builtin_amdgcn_mfma_f32_16x16x32_bf16(ah, b1l, acc1, 0, 0, 0);
            acc1 = __builtin_amdgcn_mfma_f32_16x16x32_bf16(al, b1h, acc1, 0, 0, 0);
        }
    }
    // ---- write C ----
    int crow = rowBase + wr * 16 + lk * 4;
    int ccol = colBase + wc * 32 + lr;
    #pragma unroll
    for (int r = 0; r < 4; ++r) {
        C[(size_t)(crow + r) * N + ccol]      = acc0[r];
        C[(size_t)(crow + r) * N + ccol + 16] = acc1[r];
    }
    // ---- fused adot epilogue ----
    int n0 = colBase + wc * 32 + lr;      // global col of acc0
    int hh = n0 / FO;
    int o0 = n0 % FO;
    int o1 = o0 + 16;                     // acc1's col within same head
    const float* av = a + hh * 2 * FO;
    float aS0 = av[o0], aS1 = av[o1];
    float aD0 = av[FO + o0], aD1 = av[FO + o1];
    float sv[4], dv[4];
    #pragma unroll
    for (int r = 0; r < 4; ++r) {
        sv[r] = acc0[r] * aS0 + acc1[r] * aS1;
        dv[r] = acc0[r] * aD0 + acc1[r] * aD1;
        #pragma unroll
        for (int msk = 1; msk < 16; msk <<= 1) {
            sv[r] += __shfl_xor(sv[r], msk);
            dv[r] += __shfl_xor(dv[r], msk);
        }
    }
    if constexpr (FO == 64) {
        if (lr == 0) {
            #pragma unroll
            for (int r = 0; r < 4; ++r) {
                reds[wc][wr * 16 + lk * 4 + r] = sv[r];
                redd[wc][wr * 16 + lk * 4 + r] = dv[r];
            }
        }
        __syncthreads();
        if (tid < BM) {
            int row = tid;
            asrc[by * NNODES + rowBase + row] = reds[0][row] + reds[1][row];
            adst[by * NNODES + rowBase + row] = redd[0][row] + redd[1][row];
        }
    } else {
        // FO==32: each wc half is a complete head dot
        if (lr == 0) {
            #pragma unroll
            for (int r = 0; r < 4; ++r) {
                asrc[hh * NNODES + rowBase + wr * 16 + lk * 4 + r] = sv[r];
                adst[hh * NNODES + rowBase + wr * 16 + lk * 4 + r] = dv[r];
            }
        }
    }
}

// ---------------------------------------------------------------------------
// Fused kernel: blocks [0,1024) build neighbor lists; [1024,1536) = gemm1.
// ---------------------------------------------------------------------------
__global__ __launch_bounds__(256) void fused1_kernel(
    const float* __restrict__ adj, int* __restrict__ nbr, int* __restrict__ deg,
    const float* __restrict__ x, const float* __restrict__ W1,
    const float* __restrict__ a1, float* __restrict__ Wh1,
    float* __restrict__ as1, float* __restrict__ ad1) {
    int b = blockIdx.x;
    if (b < NNODES / 4) {
        build_nbr_body(adj, nbr, deg, b);
    } else {
        int g = b - NNODES / 4;
        gemm_body<512, 256, 64>(x, W1, a1, Wh1, as1, ad1, g & 127, g >> 7);
    }
}

__global__ __launch_bounds__(256) void gemm2_kernel(
    const float* __restrict__ h1, const float* __restrict__ W2,
    const float* __restrict__ a2, float* __restrict__ Wh2,
    float* __restrict__ as2, float* __restrict__ ad2) {
    gemm_body<256, 128, 32>(h1, W2, a2, Wh2, as2, ad2, blockIdx.x, blockIdx.y);
}

// ---------------------------------------------------------------------------
// agg: sparse softmax + aggregation + ELU. One wave per (n, h), float4 gathers.
// ---------------------------------------------------------------------------
template <int FO>
__global__ __launch_bounds__(256) void agg_kernel(
    const float* __restrict__ Wh,
    const float* __restrict__ asrc, const float* __restrict__ adst,
    const int* __restrict__ nbr, const int* __restrict__ deg,
    float* __restrict__ out) {
    __shared__ float2 sw[4][NBR_STRIDE];
    int wslot = threadIdx.x >> 6;
    int lane = threadIdx.x & 63;
    int wid = blockIdx.x * 4 + wslot;
    int n = wid >> 2, h = wid & 3;
    int dg = deg[n];
    const int* lst = nbr + n * NBR_STRIDE;
    float my_as = asrc[h * NNODES + n];

    int c0 = 0, c1 = 0;
    float e0 = -1e30f, e1 = -1e30f;
    if (lane < dg) {
        c0 = lst[lane];
        float e = my_as + adst[h * NNODES + c0];
        e0 = e >= 0.f ? e : 0.2f * e;
    }
    if (lane + 64 < dg) {
        c1 = lst[lane + 64];
        float e = my_as + adst[h * NNODES + c1];
        e1 = e >= 0.f ? e : 0.2f * e;
    }
    float m = fmaxf(e0, e1);
    #pragma unroll
    for (int s = 32; s; s >>= 1) m = fmaxf(m, __shfl_xor(m, s));
    float p0 = (lane < dg) ? __expf(e0 - m) : 0.f;
    float p1 = (lane + 64 < dg) ? __expf(e1 - m) : 0.f;
    float denom = p0 + p1;
    #pragma unroll
    for (int s = 32; s; s >>= 1) denom += __shfl_xor(denom, s);
    float inv = 1.0f / denom;

    if (lane < dg)      sw[wslot][lane]      = make_float2(p0 * inv, __int_as_float(c0));
    if (lane + 64 < dg) sw[wslot][lane + 64] = make_float2(p1 * inv, __int_as_float(c1));
    __syncthreads();

    constexpr int STRIDE = NHEADS * FO;
    constexpr int LPR = FO / 4;      // lanes per neighbor row (16 or 8)
    constexpr int NPS = 64 / LPR;    // neighbors per step (4 or 8)
    int sub = lane / LPR;
    int dim4 = (lane % LPR) * 4;
    const float* whp = Wh + h * FO + dim4;
    f32x4 acc = {0.f, 0.f, 0.f, 0.f};
    int main_n = (dg / (4 * NPS)) * (4 * NPS);
    int k = 0;
    for (; k < main_n; k += 4 * NPS) {
        #pragma unroll
        for (int u = 0; u < 4; ++u) {
            float2 w = sw[wslot][k + u * NPS + sub];
            int col = __float_as_int(w.y);
            float4 v = *reinterpret_cast<const float4*>(&whp[(size_t)col * STRIDE]);
            acc[0] += w.x * v.x;
            acc[1] += w.x * v.y;
            acc[2] += w.x * v.z;
            acc[3] += w.x * v.w;
        }
    }
    for (; k < dg; k += NPS) {
        if (k + sub < dg) {
            float2 w = sw[wslot][k + sub];
            int col = __float_as_int(w.y);
            float4 v = *reinterpret_cast<const float4*>(&whp[(size_t)col * STRIDE]);
            acc[0] += w.x * v.x;
            acc[1] += w.x * v.y;
            acc[2] += w.x * v.z;
            acc[3] += w.x * v.w;
        }
    }
    #pragma unroll
    for (int s = LPR; s < 64; s <<= 1) {
        acc[0] += __shfl_xor(acc[0], s);
        acc[1] += __shfl_xor(acc[1], s);
        acc[2] += __shfl_xor(acc[2], s);
        acc[3] += __shfl_xor(acc[3], s);
    }
    if (lane < LPR) {
        float4 r;
        r.x = acc[0] > 0.f ? acc[0] : expm1f(acc[0]);
        r.y = acc[1] > 0.f ? acc[1] : expm1f(acc[1]);
        r.z = acc[2] > 0.f ? acc[2] : expm1f(acc[2]);
        r.w = acc[3] > 0.f ? acc[3] : expm1f(acc[3]);
        *reinterpret_cast<float4*>(&out[(size_t)n * STRIDE + h * FO + dim4]) = r;
    }
}

// ---------------------------------------------------------------------------
extern "C" void kernel_launch(void* const* d_in, const int* in_sizes, int n_in,
                              void* d_out, int out_size, void* d_ws, size_t ws_size,
                              hipStream_t stream) {
    const float* x   = (const float*)d_in[0];
    const float* adj = (const float*)d_in[1];
    const float* W1  = (const float*)d_in[2];
    const float* a1  = (const float*)d_in[3];
    const float* W2  = (const float*)d_in[4];
    const float* a2  = (const float*)d_in[5];
    float* out = (float*)d_out;

    char* p = (char*)d_ws;
    auto alloc = [&](size_t bytes) -> void* {
        void* r = (void*)p;
        p += (bytes + 255) & ~(size_t)255;
        return r;
    };
    int*   nbr = (int*)alloc((size_t)NNODES * NBR_STRIDE * 4);
    int*   deg = (int*)alloc((size_t)NNODES * 4);
    float* Wh1 = (float*)alloc((size_t)NNODES * 256 * 4);
    float* as1 = (float*)alloc((size_t)NHEADS * NNODES * 4);
    float* ad1 = (float*)alloc((size_t)NHEADS * NNODES * 4);
    float* h1  = (float*)alloc((size_t)NNODES * 256 * 4);
    float* Wh2 = (float*)alloc((size_t)NNODES * 128 * 4);
    float* as2 = (float*)alloc((size_t)NHEADS * NNODES * 4);
    float* ad2 = (float*)alloc((size_t)NHEADS * NNODES * 4);

    // ---- fused: build_nbr + gemm1(+adot1) ----
    fused1_kernel<<<dim3(NNODES / 4 + 512), dim3(256), 0, stream>>>(
        adj, nbr, deg, x, W1, a1, Wh1, as1, ad1);
    agg_kernel<64><<<dim3(NNODES * NHEADS / 4), dim3(256), 0, stream>>>(
        Wh1, as1, ad1, nbr, deg, h1);

    // ---- layer 2 ----
    gemm2_kernel<<<dim3(NNODES / 32, 2), dim3(256), 0, stream>>>(
        h1, W2, a2, Wh2, as2, ad2);
    agg_kernel<32><<<dim3(NNODES * NHEADS / 4), dim3(256), 0, stream>>>(
        Wh2, as2, ad2, nbr, deg, out);
}

// Round 6
// 69.702 us; speedup vs baseline: 1.2249x; 1.2249x over previous
//
#include <hip/hip_runtime.h>
#include <hip/hip_bf16.h>
#include <cstdint>
#include <cstddef>

#define NNODES 4096
#define NHEADS 4
#define NBR_STRIDE 128

typedef __attribute__((ext_vector_type(8))) short bf16x8v;
typedef __attribute__((ext_vector_type(4))) float f32x4;

__device__ inline unsigned short bf16_rn(float f) {
    unsigned int u = __float_as_uint(f);
    u += 0x7FFFu + ((u >> 16) & 1u);
    return (unsigned short)(u >> 16);
}
__device__ inline float bf16_f32(unsigned short s) {
    return __uint_as_float(((unsigned int)s) << 16);
}

// ---------------------------------------------------------------------------
// Kernel 1: build neighbor lists. One wave per row. ALL 16 float4 loads are
// hoisted into registers first (64 VGPR) so the whole 16KB row is in flight
// before the serial ballot/compaction chain starts.
// ---------------------------------------------------------------------------
__global__ __launch_bounds__(256) void build_nbr_kernel(
    const float* __restrict__ adj, int* __restrict__ nbr, int* __restrict__ deg) {
    int wave = threadIdx.x >> 6;
    int lane = threadIdx.x & 63;
    int row = blockIdx.x * 4 + wave;
    const float4* arow = reinterpret_cast<const float4*>(adj + (size_t)row * NNODES);
    float4 v[16];
    #pragma unroll
    for (int it = 0; it < 16; ++it) v[it] = arow[it * 64 + lane];
    unsigned long long lt = (1ull << lane) - 1ull;
    int base = 0;
    #pragma unroll
    for (int it = 0; it < 16; ++it) {
        bool b0 = v[it].x > 0.f, b1 = v[it].y > 0.f, b2 = v[it].z > 0.f, b3 = v[it].w > 0.f;
        unsigned long long m0 = __ballot(b0);
        unsigned long long m1 = __ballot(b1);
        unsigned long long m2 = __ballot(b2);
        unsigned long long m3 = __ballot(b3);
        int pre = __popcll(m0 & lt) + __popcll(m1 & lt) +
                  __popcll(m2 & lt) + __popcll(m3 & lt);
        int pos = base + pre;
        int colb = it * 256 + lane * 4;
        if (b0) { if (pos < NBR_STRIDE) nbr[row * NBR_STRIDE + pos] = colb;     pos++; }
        if (b1) { if (pos < NBR_STRIDE) nbr[row * NBR_STRIDE + pos] = colb + 1; pos++; }
        if (b2) { if (pos < NBR_STRIDE) nbr[row * NBR_STRIDE + pos] = colb + 2; pos++; }
        if (b3) { if (pos < NBR_STRIDE) nbr[row * NBR_STRIDE + pos] = colb + 3; pos++; }
        base += __popcll(m0) + __popcll(m1) + __popcll(m2) + __popcll(m3);
    }
    if (lane == 0) deg[row] = base < NBR_STRIDE ? base : NBR_STRIDE;
}

// ---------------------------------------------------------------------------
// Kernel 2: pack BOTH layers' W -> transposed hi/lo bf16  Bt[N][K]
// ---------------------------------------------------------------------------
__global__ __launch_bounds__(256) void pack_b_both_kernel(
    const float* __restrict__ W1, const float* __restrict__ W2,
    unsigned short* __restrict__ B1h, unsigned short* __restrict__ B1l,
    unsigned short* __restrict__ B2h, unsigned short* __restrict__ B2l) {
    int t = blockIdx.x * 256 + threadIdx.x;
    if (t < 256 * 512) {
        int n = t >> 9, k = t & 511;
        int h = n >> 6, o = n & 63;
        float v = W1[((size_t)h * 512 + k) * 64 + o];
        unsigned short hi = bf16_rn(v);
        B1h[t] = hi;
        B1l[t] = bf16_rn(v - bf16_f32(hi));
    } else {
        int u = t - 256 * 512;
        if (u < 128 * 256) {
            int n = u >> 8, k = u & 255;
            int h = n >> 5, o = n & 31;
            float v = W2[((size_t)h * 256 + k) * 32 + o];
            unsigned short hi = bf16_rn(v);
            B2h[u] = hi;
            B2l[u] = bf16_rn(v - bf16_f32(hi));
        }
    }
}

// ---------------------------------------------------------------------------
// Kernel 3: MFMA GEMM, in-kernel A hi/lo split, pre-packed B hi/lo.
// C[M,N] = A[M,K](f32) * Bt[N,K]^T via hi*hi + hi*lo + lo*hi.
// BM=32, BN=64, BK=64; 4 waves, wave = 16 rows x 32 cols (2 frags).
// Epilogue additionally computes per-row attention dots (fused adot).
// ---------------------------------------------------------------------------
template <int K, int N, int FO>
__global__ __launch_bounds__(256) void gemm_split_kernel(
    const float* __restrict__ A,
    const unsigned short* __restrict__ Bh, const unsigned short* __restrict__ Bl,
    const float* __restrict__ a, float* __restrict__ C,
    float* __restrict__ asrc, float* __restrict__ adst) {
    constexpr int BM = 32, BN = 64, BK = 64, LP = BK + 8;
    __shared__ unsigned short Alh[BM][LP], All[BM][LP];
    __shared__ unsigned short Blh[BN][LP], Bll[BN][LP];
    __shared__ float reds[2][BM], redd[2][BM];
    int tid = threadIdx.x;
    int wave = tid >> 6, lane = tid & 63;
    int rowBase = blockIdx.x * BM;
    int colBase = blockIdx.y * BN;
    int wr = wave >> 1, wc = wave & 1;
    int lr = lane & 15, lk = lane >> 4;
    f32x4 acc0 = {0.f, 0.f, 0.f, 0.f};
    f32x4 acc1 = {0.f, 0.f, 0.f, 0.f};
    int ar = tid >> 3;            // 0..31
    int ac = (tid & 7) * 8;       // 8-elem chunks
    for (int k0 = 0; k0 < K; k0 += BK) {
        float4 a0 = *reinterpret_cast<const float4*>(&A[(size_t)(rowBase + ar) * K + k0 + ac]);
        float4 a1 = *reinterpret_cast<const float4*>(&A[(size_t)(rowBase + ar) * K + k0 + ac + 4]);
        uint4 bh0 = *reinterpret_cast<const uint4*>(&Bh[(size_t)(colBase + ar) * K + k0 + ac]);
        uint4 bl0 = *reinterpret_cast<const uint4*>(&Bl[(size_t)(colBase + ar) * K + k0 + ac]);
        uint4 bh1 = *reinterpret_cast<const uint4*>(&Bh[(size_t)(colBase + 32 + ar) * K + k0 + ac]);
        uint4 bl1 = *reinterpret_cast<const uint4*>(&Bl[(size_t)(colBase + 32 + ar) * K + k0 + ac]);
        __syncthreads();   // previous iteration's readers done
        ushort4 h4, l4;
        h4.x = bf16_rn(a0.x); l4.x = bf16_rn(a0.x - bf16_f32(h4.x));
        h4.y = bf16_rn(a0.y); l4.y = bf16_rn(a0.y - bf16_f32(h4.y));
        h4.z = bf16_rn(a0.z); l4.z = bf16_rn(a0.z - bf16_f32(h4.z));
        h4.w = bf16_rn(a0.w); l4.w = bf16_rn(a0.w - bf16_f32(h4.w));
        *reinterpret_cast<ushort4*>(&Alh[ar][ac]) = h4;
        *reinterpret_cast<ushort4*>(&All[ar][ac]) = l4;
        h4.x = bf16_rn(a1.x); l4.x = bf16_rn(a1.x - bf16_f32(h4.x));
        h4.y = bf16_rn(a1.y); l4.y = bf16_rn(a1.y - bf16_f32(h4.y));
        h4.z = bf16_rn(a1.z); l4.z = bf16_rn(a1.z - bf16_f32(h4.z));
        h4.w = bf16_rn(a1.w); l4.w = bf16_rn(a1.w - bf16_f32(h4.w));
        *reinterpret_cast<ushort4*>(&Alh[ar][ac + 4]) = h4;
        *reinterpret_cast<ushort4*>(&All[ar][ac + 4]) = l4;
        *reinterpret_cast<uint4*>(&Blh[ar][ac]) = bh0;
        *reinterpret_cast<uint4*>(&Bll[ar][ac]) = bl0;
        *reinterpret_cast<uint4*>(&Blh[32 + ar][ac]) = bh1;
        *reinterpret_cast<uint4*>(&Bll[32 + ar][ac]) = bl1;
        __syncthreads();
        #pragma unroll
        for (int ks = 0; ks < 2; ++ks) {
            int kb = ks * 32 + lk * 8;
            bf16x8v ah = *reinterpret_cast<const bf16x8v*>(&Alh[wr * 16 + lr][kb]);
            bf16x8v al = *reinterpret_cast<const bf16x8v*>(&All[wr * 16 + lr][kb]);
            bf16x8v b0h = *reinterpret_cast<const bf16x8v*>(&Blh[wc * 32 + lr][kb]);
            bf16x8v b0l = *reinterpret_cast<const bf16x8v*>(&Bll[wc * 32 + lr][kb]);
            bf16x8v b1h = *reinterpret_cast<const bf16x8v*>(&Blh[wc * 32 + 16 + lr][kb]);
            bf16x8v b1l = *reinterpret_cast<const bf16x8v*>(&Bll[wc * 32 + 16 + lr][kb]);
            acc0 = __builtin_amdgcn_mfma_f32_16x16x32_bf16(ah, b0h, acc0, 0, 0, 0);
            acc0 = __builtin_amdgcn_mfma_f32_16x16x32_bf16(ah, b0l, acc0, 0, 0, 0);
            acc0 = __builtin_amdgcn_mfma_f32_16x16x32_bf16(al, b0h, acc0, 0, 0, 0);
            acc1 = __builtin_amdgcn_mfma_f32_16x16x32_bf16(ah, b1h, acc1, 0, 0, 0);
            acc1 = __builtin_amdgcn_mfma_f32_16x16x32_bf16(ah, b1l, acc1, 0, 0, 0);
            acc1 = __builtin_amdgcn_mfma_f32_16x16x32_bf16(al, b1h, acc1, 0, 0, 0);
        }
    }
    // ---- write C ----
    int crow = rowBase + wr * 16 + lk * 4;
    int ccol = colBase + wc * 32 + lr;
    #pragma unroll
    for (int r = 0; r < 4; ++r) {
        C[(size_t)(crow + r) * N + ccol]      = acc0[r];
        C[(size_t)(crow + r) * N + ccol + 16] = acc1[r];
    }
    // ---- fused adot epilogue ----
    int n0 = colBase + wc * 32 + lr;      // global col of acc0
    int hh = n0 / FO;
    int o0 = n0 % FO;
    int o1 = o0 + 16;
    const float* av = a + hh * 2 * FO;
    float aS0 = av[o0], aS1 = av[o1];
    float aD0 = av[FO + o0], aD1 = av[FO + o1];
    float sv[4], dv[4];
    #pragma unroll
    for (int r = 0; r < 4; ++r) {
        sv[r] = acc0[r] * aS0 + acc1[r] * aS1;
        dv[r] = acc0[r] * aD0 + acc1[r] * aD1;
        #pragma unroll
        for (int msk = 1; msk < 16; msk <<= 1) {
            sv[r] += __shfl_xor(sv[r], msk);
            dv[r] += __shfl_xor(dv[r], msk);
        }
    }
    if constexpr (FO == 64) {
        if (lr == 0) {
            #pragma unroll
            for (int r = 0; r < 4; ++r) {
                reds[wc][wr * 16 + lk * 4 + r] = sv[r];
                redd[wc][wr * 16 + lk * 4 + r] = dv[r];
            }
        }
        __syncthreads();
        if (tid < BM) {
            int row = tid;
            asrc[blockIdx.y * NNODES + rowBase + row] = reds[0][row] + reds[1][row];
            adst[blockIdx.y * NNODES + rowBase + row] = redd[0][row] + redd[1][row];
        }
    } else {
        if (lr == 0) {
            #pragma unroll
            for (int r = 0; r < 4; ++r) {
                asrc[hh * NNODES + rowBase + wr * 16 + lk * 4 + r] = sv[r];
                adst[hh * NNODES + rowBase + wr * 16 + lk * 4 + r] = dv[r];
            }
        }
    }
}

// ---------------------------------------------------------------------------
// Kernel 4: sparse softmax + aggregation + ELU. One wave per (n, h).
// ---------------------------------------------------------------------------
template <int FO>
__global__ __launch_bounds__(256) void agg_kernel(
    const float* __restrict__ Wh,
    const float* __restrict__ asrc, const float* __restrict__ adst,
    const int* __restrict__ nbr, const int* __restrict__ deg,
    float* __restrict__ out) {
    __shared__ float2 sw[4][NBR_STRIDE];
    int wslot = threadIdx.x >> 6;
    int lane = threadIdx.x & 63;
    int wid = blockIdx.x * 4 + wslot;
    int n = wid >> 2, h = wid & 3;
    int dg = deg[n];
    const int* lst = nbr + n * NBR_STRIDE;
    float my_as = asrc[h * NNODES + n];

    int c0 = 0, c1 = 0;
    float e0 = -1e30f, e1 = -1e30f;
    if (lane < dg) {
        c0 = lst[lane];
        float e = my_as + adst[h * NNODES + c0];
        e0 = e >= 0.f ? e : 0.2f * e;
    }
    if (lane + 64 < dg) {
        c1 = lst[lane + 64];
        float e = my_as + adst[h * NNODES + c1];
        e1 = e >= 0.f ? e : 0.2f * e;
    }
    float m = fmaxf(e0, e1);
    #pragma unroll
    for (int s = 32; s; s >>= 1) m = fmaxf(m, __shfl_xor(m, s));
    float p0 = (lane < dg) ? __expf(e0 - m) : 0.f;
    float p1 = (lane + 64 < dg) ? __expf(e1 - m) : 0.f;
    float denom = p0 + p1;
    #pragma unroll
    for (int s = 32; s; s >>= 1) denom += __shfl_xor(denom, s);
    float inv = 1.0f / denom;

    if (lane < dg)      sw[wslot][lane]      = make_float2(p0 * inv, __int_as_float(c0));
    if (lane + 64 < dg) sw[wslot][lane + 64] = make_float2(p1 * inv, __int_as_float(c1));
    __syncthreads();

    constexpr int STRIDE = NHEADS * FO;
    constexpr int LPR = FO / 4;      // lanes per neighbor row (16 or 8)
    constexpr int NPS = 64 / LPR;    // neighbors per step (4 or 8)
    int sub = lane / LPR;
    int dim4 = (lane % LPR) * 4;
    const float* whp = Wh + h * FO + dim4;
    f32x4 acc = {0.f, 0.f, 0.f, 0.f};
    int main_n = (dg / (4 * NPS)) * (4 * NPS);
    int k = 0;
    for (; k < main_n; k += 4 * NPS) {
        #pragma unroll
        for (int u = 0; u < 4; ++u) {
            float2 w = sw[wslot][k + u * NPS + sub];
            int col = __float_as_int(w.y);
            float4 v = *reinterpret_cast<const float4*>(&whp[(size_t)col * STRIDE]);
            acc[0] += w.x * v.x;
            acc[1] += w.x * v.y;
            acc[2] += w.x * v.z;
            acc[3] += w.x * v.w;
        }
    }
    for (; k < dg; k += NPS) {
        if (k + sub < dg) {
            float2 w = sw[wslot][k + sub];
            int col = __float_as_int(w.y);
            float4 v = *reinterpret_cast<const float4*>(&whp[(size_t)col * STRIDE]);
            acc[0] += w.x * v.x;
            acc[1] += w.x * v.y;
            acc[2] += w.x * v.z;
            acc[3] += w.x * v.w;
        }
    }
    #pragma unroll
    for (int s = LPR; s < 64; s <<= 1) {
        acc[0] += __shfl_xor(acc[0], s);
        acc[1] += __shfl_xor(acc[1], s);
        acc[2] += __shfl_xor(acc[2], s);
        acc[3] += __shfl_xor(acc[3], s);
    }
    if (lane < LPR) {
        float4 r;
        r.x = acc[0] > 0.f ? acc[0] : expm1f(acc[0]);
        r.y = acc[1] > 0.f ? acc[1] : expm1f(acc[1]);
        r.z = acc[2] > 0.f ? acc[2] : expm1f(acc[2]);
        r.w = acc[3] > 0.f ? acc[3] : expm1f(acc[3]);
        *reinterpret_cast<float4*>(&out[(size_t)n * STRIDE + h * FO + dim4]) = r;
    }
}

// ---------------------------------------------------------------------------
extern "C" void kernel_launch(void* const* d_in, const int* in_sizes, int n_in,
                              void* d_out, int out_size, void* d_ws, size_t ws_size,
                              hipStream_t stream) {
    const float* x   = (const float*)d_in[0];
    const float* adj = (const float*)d_in[1];
    const float* W1  = (const float*)d_in[2];
    const float* a1  = (const float*)d_in[3];
    const float* W2  = (const float*)d_in[4];
    const float* a2  = (const float*)d_in[5];
    float* out = (float*)d_out;

    char* p = (char*)d_ws;
    auto alloc = [&](size_t bytes) -> void* {
        void* r = (void*)p;
        p += (bytes + 255) & ~(size_t)255;
        return r;
    };
    int*   nbr = (int*)alloc((size_t)NNODES * NBR_STRIDE * 4);
    int*   deg = (int*)alloc((size_t)NNODES * 4);
    unsigned short* B1h = (unsigned short*)alloc((size_t)256 * 512 * 2);
    unsigned short* B1l = (unsigned short*)alloc((size_t)256 * 512 * 2);
    unsigned short* B2h = (unsigned short*)alloc((size_t)128 * 256 * 2);
    unsigned short* B2l = (unsigned short*)alloc((size_t)128 * 256 * 2);
    float* Wh1 = (float*)alloc((size_t)NNODES * 256 * 4);
    float* as1 = (float*)alloc((size_t)NHEADS * NNODES * 4);
    float* ad1 = (float*)alloc((size_t)NHEADS * NNODES * 4);
    float* h1  = (float*)alloc((size_t)NNODES * 256 * 4);
    float* Wh2 = (float*)alloc((size_t)NNODES * 128 * 4);
    float* as2 = (float*)alloc((size_t)NHEADS * NNODES * 4);
    float* ad2 = (float*)alloc((size_t)NHEADS * NNODES * 4);

    // ---- independent prep ----
    pack_b_both_kernel<<<dim3((256 * 512 + 128 * 256) / 256), dim3(256), 0, stream>>>(
        W1, W2, B1h, B1l, B2h, B2l);
    build_nbr_kernel<<<dim3(NNODES / 4), dim3(256), 0, stream>>>(adj, nbr, deg);

    // ---- layer 1 ----
    gemm_split_kernel<512, 256, 64><<<dim3(NNODES / 32, 4), dim3(256), 0, stream>>>(
        x, B1h, B1l, a1, Wh1, as1, ad1);
    agg_kernel<64><<<dim3(NNODES * NHEADS / 4), dim3(256), 0, stream>>>(
        Wh1, as1, ad1, nbr, deg, h1);

    // ---- layer 2 ----
    gemm_split_kernel<256, 128, 32><<<dim3(NNODES / 32, 2), dim3(256), 0, stream>>>(
        h1, B2h, B2l, a2, Wh2, as2, ad2);
    agg_kernel<32><<<dim3(NNODES * NHEADS / 4), dim3(256), 0, stream>>>(
        Wh2, as2, ad2, nbr, deg, out);
}